// Round 12
// baseline (419.176 us; speedup 1.0000x reference)
//
#include <hip/hip_runtime.h>
#include <math.h>

#define BB  2
#define SS  4096
#define EE  1024
#define HH  16
#define DD  64
#define WW  256
#define NCC 16   // SS / WW
#define MTOT (BB*SS)   // 8192

typedef __attribute__((ext_vector_type(4))) float f32x4;
typedef __attribute__((ext_vector_type(8))) short bf16x8;

// ---------------------------------------------------------------------------
// async global->LDS, 16B per lane. LDS dest must be wave-uniform base
// (+lane*16 is applied by HW); global src is per-lane.
// ---------------------------------------------------------------------------
__device__ __forceinline__ void gl_lds16(const void* g, void* l) {
  __builtin_amdgcn_global_load_lds(
      (const __attribute__((address_space(1))) unsigned int*)g,
      (__attribute__((address_space(3))) unsigned int*)l,
      16, 0, 0);
}

__device__ __forceinline__ unsigned bf16rne(float f) {
  unsigned u = __float_as_uint(f);
  return (u + (((u >> 16) & 1u) + 0x7fffu)) >> 16;
}

__device__ __forceinline__ unsigned long long pack64(unsigned a, unsigned b,
                                                     unsigned c2, unsigned d) {
  return (unsigned long long)(a | (b << 16)) |
         ((unsigned long long)(c2 | (d << 16)) << 32);
}

// ---------------------------------------------------------------------------
// Fused split pass: fp32 -> bf16 hi (truncated) + bf16 lo (RNE of residual)
// for hidden_states and the three weight matrices in ONE dispatch.
// ---------------------------------------------------------------------------
__global__ __launch_bounds__(256) void split_all(
    const float* __restrict__ hs, const float* __restrict__ Wq,
    const float* __restrict__ Wk, const float* __restrict__ Wv,
    unsigned short* __restrict__ Ahi, unsigned short* __restrict__ Alo,
    unsigned short* __restrict__ Wqh, unsigned short* __restrict__ Wql,
    unsigned short* __restrict__ Wkh, unsigned short* __restrict__ Wkl,
    unsigned short* __restrict__ Wvh, unsigned short* __restrict__ Wvl)
{
  const int bx = blockIdx.x;
  const float* src; unsigned short *hi, *lo; size_t blk;
  if (bx < 8192)       { src = hs; hi = Ahi; lo = Alo; blk = bx; }
  else if (bx < 9216)  { src = Wq; hi = Wqh; lo = Wql; blk = bx - 8192; }
  else if (bx < 10240) { src = Wk; hi = Wkh; lo = Wkl; blk = bx - 9216; }
  else                 { src = Wv; hi = Wvh; lo = Wvl; blk = bx - 10240; }

  const size_t i = blk * 256 + threadIdx.x;
  const float4 v = ((const float4*)src)[i];
  float f[4] = {v.x, v.y, v.z, v.w};
  unsigned short h[4], l[4];
  #pragma unroll
  for (int j = 0; j < 4; ++j) {
    unsigned u  = __float_as_uint(f[j]);
    unsigned uh = u & 0xFFFF0000u;
    h[j] = (unsigned short)(uh >> 16);
    float r = f[j] - __uint_as_float(uh);
    unsigned ur = __float_as_uint(r);
    ur += ((ur >> 16) & 1u) + 0x7FFFu;
    l[j] = (unsigned short)(ur >> 16);
  }
  *(ushort4*)&hi[4*i] = make_ushort4(h[0], h[1], h[2], h[3]);
  *(ushort4*)&lo[4*i] = make_ushort4(l[0], l[1], l[2], l[3]);
}

// ---------------------------------------------------------------------------
// bf16x3-split MFMA projection GEMM: out = (A @ W^T + b) * scale.
// R12: B (weights) now loads DIRECTLY global->registers, 1 step ahead, under
// the counted-vmcnt pipeline -- halves the LDS-port traffic that bound
// R8-R11 (~2100 cyc/step LDS vs 466 MFMA). R6's regression came from its
// vmcnt(0)-draining __syncthreads, not from B-in-regs itself; here B(t+1)
// has a full iteration (~4000 cyc) in flight before use. A stays on the
// 3-buffer gl_lds pipeline (96 KB). MFMA accumulation order unchanged
// -> bit-identical numerics. Epilogue: LDS-transpose coalesced stores.
// ---------------------------------------------------------------------------
struct ProjArgs {
  const unsigned short* Wh;
  const unsigned short* Wl;
  const float* bias;
  unsigned short* outHi;
  unsigned short* outLo;
  float scale;
};

__global__ __launch_bounds__(512) void mfma_proj(
    const unsigned short* __restrict__ Ahi,
    const unsigned short* __restrict__ Alo,
    ProjArgs p0, ProjArgs p1, ProjArgs p2)
{
  // staging: 3 bufs x [Ah 16K | Al 16K] = 96 KB, reused as the epilogue
  // transpose tile [128 rows][136 shorts] (34.8 KB).
  __shared__ __align__(16) union {
    unsigned short stage[3][16384];     // 32 KB per buffer (in shorts)
    unsigned short ep[128][136];
  } sh;

  const int tid  = threadIdx.x;
  const int lane = tid & 63;
  const int wid  = tid >> 6;          // 0..7
  const int wr   = wid >> 1;          // 0..3  (M)
  const int wc   = wid & 1;           // 0..1  (N)
  const int m0   = blockIdx.x * 256, n0 = blockIdx.y * 128;
  const ProjArgs P = (blockIdx.z == 0) ? p0 : ((blockIdx.z == 1) ? p1 : p2);

  // A staging maps: chunk q (16B) -> row = ((q>>5)<<3)|(q&7), kc = (q>>3)&3
  const int qA0 = tid, qA1 = 512 + tid;
  const int rowA0 = ((qA0 >> 5) << 3) | (qA0 & 7), kcA0 = (qA0 >> 3) & 3;
  const int rowA1 = ((qA1 >> 5) << 3) | (qA1 & 7), kcA1 = (qA1 >> 3) & 3;

  const size_t aoff0 = (size_t)(m0 + rowA0) * 2048 + (size_t)(kcA0 * 16);
  const size_t aoff1 = (size_t)(m0 + rowA1) * 2048 + (size_t)(kcA1 * 16);

  const int dstA0 = wid * 1024;            // wave-uniform LDS byte bases
  const int dstA1 = 8192 + wid * 1024;

  const char* gAh = (const char*)Ahi;
  const char* gAl = (const char*)Alo;
  const unsigned short* gBh16 = P.Wh;
  const unsigned short* gBl16 = P.Wl;

  const int fr = lane & 15;
  const int kc = lane >> 4;
  int a_o[4];
  unsigned b_go[4];   // element offsets of this lane's B-frags (ks=0)
  #pragma unroll
  for (int f = 0; f < 4; ++f) {
    int r = wr * 64 + f * 16 + fr;                       // 0..255
    a_o[f] = ((r >> 3) << 9) | (kc << 7) | ((r & 7) << 4);
    b_go[f] = (unsigned)((n0 + wc * 64 + f * 16 + fr) * EE + kc * 8);
  }

  f32x4 acc[4][4];
  #pragma unroll
  for (int i = 0; i < 4; ++i)
    #pragma unroll
    for (int j = 0; j < 4; ++j) acc[i][j] = (f32x4){0.f, 0.f, 0.f, 0.f};

  char* const Lp = (char*)&sh.stage[0][0];
  // buffer b plane bases: Ah=0, Al=16384
  #define PL(b, p) (Lp + ((b) * 32768 + (p)))

  #define STAGE(buf, ks) { const size_t kb = (size_t)(ks) * 64; \
    gl_lds16(gAh + aoff0 + kb, PL(buf,0)     + dstA0); \
    gl_lds16(gAh + aoff1 + kb, PL(buf,0)     + dstA1); \
    gl_lds16(gAl + aoff0 + kb, PL(buf,16384) + dstA0); \
    gl_lds16(gAl + aoff1 + kb, PL(buf,16384) + dstA1); }

  #define LOADB(BH, BL, ks) { \
    _Pragma("unroll") \
    for (int f = 0; f < 4; ++f) { \
      BH[f] = *(const bf16x8*)(gBh16 + b_go[f] + (unsigned)((ks) * 32)); \
      BL[f] = *(const bf16x8*)(gBl16 + b_go[f] + (unsigned)((ks) * 32)); \
    } }

  bf16x8 ah0[4], ah1[4];                 // two A-c1 register sets
  bf16x8 al[4];                          // A-c2 set (single)
  bf16x8 b0h[4], b0l[4], b1h[4], b1l[4]; // two B register sets

  #define RD_C1(AH, buf) { \
    _Pragma("unroll") \
    for (int f = 0; f < 4; ++f) \
      AH[f] = *(const bf16x8*)(PL(buf,0) + a_o[f]); }
  #define RD_C2(buf) { \
    _Pragma("unroll") \
    for (int f = 0; f < 4; ++f) \
      al[f] = *(const bf16x8*)(PL(buf,16384) + a_o[f]); }

  #define MM16(AA, BBV) { \
    _Pragma("unroll") \
    for (int i = 0; i < 4; ++i) \
      _Pragma("unroll") \
      for (int j = 0; j < 4; ++j) \
        acc[i][j] = __builtin_amdgcn_mfma_f32_16x16x32_bf16(AA[i], BBV[j], acc[i][j], 0,0,0); }

  // One pipeline iteration. All control args are literals.
  // Stream per iter: [B(t+1) x8 early] ... [A(t+3) x4 late] -> the B(t)
  // auto-wait before the first MFMA keeps A(t+2..3)/B(t+1) in flight.
  #define ITER(KS, B, BN, AHc, AHn, BHc, BLc, BHn, BLn, VM, DOSTAGE, DOLOADB, DONEXT) { \
    RD_C2(B); \
    if (DOLOADB) LOADB(BHn, BLn, (KS)+1); \
    __builtin_amdgcn_sched_barrier(0); \
    asm volatile("s_waitcnt lgkmcnt(4)" ::: "memory");   /* c1 regs ready */ \
    __builtin_amdgcn_sched_barrier(0); \
    __builtin_amdgcn_s_setprio(1); \
    MM16(AHc, BHc);                                      /* ah*bh */ \
    __builtin_amdgcn_s_setprio(0); \
    __builtin_amdgcn_sched_barrier(0); \
    asm volatile("s_waitcnt lgkmcnt(0)" ::: "memory");   /* c2 ready; buf free */ \
    __builtin_amdgcn_sched_barrier(0); \
    __builtin_amdgcn_s_barrier();                        /* all waves done with B */ \
    if (DOSTAGE) STAGE(B, (KS)+3); \
    if (VM == 20)      { asm volatile("s_waitcnt vmcnt(20)" ::: "memory"); } \
    else if (VM == 16) { asm volatile("s_waitcnt vmcnt(16)" ::: "memory"); } \
    else if (VM == 12) { asm volatile("s_waitcnt vmcnt(12)" ::: "memory"); } \
    else if (VM == 0)  { asm volatile("s_waitcnt vmcnt(0)"  ::: "memory"); } \
    if (VM >= 0) { __builtin_amdgcn_sched_barrier(0); __builtin_amdgcn_s_barrier(); } \
    if (DONEXT) RD_C1(AHn, BN); \
    __builtin_amdgcn_s_setprio(1); \
    MM16(AHc, BLc);                                      /* ah*bl */ \
    MM16(al, BHc);                                       /* al*bh */ \
    __builtin_amdgcn_s_setprio(0); \
  }

  // prologue: 3 A-tiles + B(0) in flight; tile 0 certified; preload c1.
  STAGE(0, 0);
  LOADB(b0h, b0l, 0);
  STAGE(1, 1);
  STAGE(2, 2);
  asm volatile("s_waitcnt vmcnt(8)" ::: "memory");   // A(0)+B(0) done
  __builtin_amdgcn_sched_barrier(0);
  __builtin_amdgcn_s_barrier();
  RD_C1(ah0, 0);

  ITER(0, 0, 1, ah0, ah1, b0h, b0l, b1h, b1l, 12, 1, 1, 1);
  ITER(1, 1, 2, ah1, ah0, b1h, b1l, b0h, b0l, 20, 1, 1, 1);
  for (int kk = 2; kk < 26; kk += 6) {
    ITER(kk+0, 2, 0, ah0, ah1, b0h, b0l, b1h, b1l, 20, 1, 1, 1);
    ITER(kk+1, 0, 1, ah1, ah0, b1h, b1l, b0h, b0l, 20, 1, 1, 1);
    ITER(kk+2, 1, 2, ah0, ah1, b0h, b0l, b1h, b1l, 20, 1, 1, 1);
    ITER(kk+3, 2, 0, ah1, ah0, b1h, b1l, b0h, b0l, 20, 1, 1, 1);
    ITER(kk+4, 0, 1, ah0, ah1, b0h, b0l, b1h, b1l, 20, 1, 1, 1);
    ITER(kk+5, 1, 2, ah1, ah0, b1h, b1l, b0h, b0l, 20, 1, 1, 1);
  }
  // peeled tail: ks = 26..31 (A-stage ends at ks=28, B-load at ks=30)
  ITER(26, 2, 0, ah0, ah1, b0h, b0l, b1h, b1l, 20, 1, 1, 1);
  ITER(27, 0, 1, ah1, ah0, b1h, b1l, b0h, b0l, 20, 1, 1, 1);
  ITER(28, 1, 2, ah0, ah1, b0h, b0l, b1h, b1l, 20, 1, 1, 1);
  ITER(29, 2, 0, ah1, ah0, b1h, b1l, b0h, b0l, 20, 0, 1, 1);
  ITER(30, 0, 1, ah0, ah1, b0h, b0l, b1h, b1l, 16, 0, 1, 1);
  ITER(31, 1, 2, ah1, ah0, b1h, b1l, b0h, b0l, -1, 0, 0, 0);
  #undef PL
  #undef STAGE
  #undef LOADB
  #undef RD_C1
  #undef RD_C2
  #undef MM16
  #undef ITER

  // -------------------------------------------------------------------------
  // Epilogue: 2 row-halves x 2 planes. Scatter fragment shorts into the LDS
  // tile (XOR chunk swizzle c16 ^= row&7), then 16B-coalesced global stores.
  // -------------------------------------------------------------------------
  const int r4 = (lane >> 4) << 2;
  #pragma unroll
  for (int hh = 0; hh < 2; ++hh) {
    #pragma unroll
    for (int plane = 0; plane < 2; ++plane) {
      __syncthreads();
      if ((wr >> 1) == hh) {
        #pragma unroll
        for (int j = 0; j < 4; ++j) {
          const int col_l = wc*64 + j*16 + fr;
          const float bv = P.bias[n0 + col_l];
          #pragma unroll
          for (int i = 0; i < 4; ++i) {
            const int rl0 = (wr & 1)*64 + i*16 + r4;
            #pragma unroll
            for (int v = 0; v < 4; ++v) {
              const float val = (acc[i][j][v] + bv) * P.scale;
              const unsigned u = __float_as_uint(val);
              unsigned sv;
              if (plane == 0) { sv = u >> 16; }
              else {
                const float rres = val - __uint_as_float(u & 0xFFFF0000u);
                unsigned ur = __float_as_uint(rres);
                ur += ((ur >> 16) & 1u) + 0x7FFFu; sv = ur >> 16;
              }
              const int rl = rl0 + v;
              sh.ep[rl][(((col_l >> 3) ^ (rl & 7)) << 3) + (col_l & 7)] =
                  (unsigned short)sv;
            }
          }
        }
      }
      __syncthreads();
      unsigned short* const OUT = plane ? P.outLo : P.outHi;
      #pragma unroll
      for (int u2 = 0; u2 < 4; ++u2) {
        const int chunk = u2 * 512 + tid;       // 2048 chunks = 128x128
        const int rr = chunk >> 4, c16 = chunk & 15;
        const bf16x8 vv = *(const bf16x8*)&sh.ep[rr][(c16 ^ (rr & 7)) << 3];
        *(bf16x8*)&OUT[(size_t)(m0 + hh*128 + rr) * EE + n0 + c16*8] = vv;
      }
    }
  }
}

// ---------------------------------------------------------------------------
// MFMA fused no-overlap sliding-chunk attention (unchanged from passing R11).
// Chunk split into TWO blocks of 128 q-rows (grid z = BB*2) for TLP.
// ---------------------------------------------------------------------------
__global__ __launch_bounds__(256) void attn_mfma(
    const unsigned short* __restrict__ Qh_g, const unsigned short* __restrict__ Ql_g,
    const unsigned short* __restrict__ Kh_g, const unsigned short* __restrict__ Kl_g,
    const unsigned short* __restrict__ Vh_g, const unsigned short* __restrict__ Vl_g,
    float* __restrict__ Og)
{
  __shared__ __align__(16) unsigned short Kf[2][2048];   // [plane][frag-linear]
  __shared__ __align__(16) unsigned short Vt[2][2048];   // [plane][V^T frag-linear, swz]
  __shared__ unsigned long long Pscr[4][256];            // per wave: hi[0:128) lo[128:256)

  const int c = blockIdx.x, h = blockIdx.y, bz = blockIdx.z;
  const int b = bz >> 1, qh = bz & 1;          // batch, q-half of the chunk
  const int tid = threadIdx.x;
  const int lane = tid & 63, wid = tid >> 6;
  const int g = lane >> 4, lq = lane & 15;

  const size_t chunk0 = (size_t)(b * NCC + c) * WW;   // chunk row start
  const size_t qrow0  = chunk0 + (size_t)qh * 128;    // this block's q rows
  const int colh = h * DD;

  // ---- Q B-frags (col q = lane&15, k-elems d = g*8..), 2 subtiles/wave ----
  bf16x8 qfh[2][2], qfl[2][2];
  #pragma unroll
  for (int s = 0; s < 2; ++s)
    #pragma unroll
    for (int ch = 0; ch < 2; ++ch) {
      const size_t off = (qrow0 + wid*32 + s*16 + lq) * EE + colh + ch*32 + g*8;
      qfh[s][ch] = *(const bf16x8*)(Qh_g + off);
      qfl[s][ch] = *(const bf16x8*)(Ql_g + off);
    }

  f32x4 Oa[4][2];   // [d-subtile][q-subtile]
  #pragma unroll
  for (int i = 0; i < 4; ++i)
    #pragma unroll
    for (int j = 0; j < 2; ++j) Oa[i][j] = (f32x4){0.f, 0.f, 0.f, 0.f};
  float m[2], lsum[2];
  #pragma unroll
  for (int s = 0; s < 2; ++s) { m[s] = -1e30f; lsum[s] = 0.f; }

  // K staging: wave wid stages A-frag f=wid (kh=wid&1, ch=wid>>1), frag-linear.
  const int kK = 16*(wid & 1) + lq;
  const int dK = 32*(wid >> 1) + g*8;
  // V staging: thread holds V[kV][dV..dV+7]; scattered to V^T frag-linear.
  const int stv = tid >> 5, idxv = tid & 31;
  const int kV = 16*(stv >> 2) + (idxv >> 1);
  const int dV = 16*(stv & 3) + 8*(idxv & 1);
  const int C0  = ((dV >> 4) << 6) | ((kV >> 3) << 4) | (dV & 15);
  const int swW = (((dV >> 4) & 1) << 2) | (((kV >> 3) & 1) << 1) | ((dV >> 3) & 1);
  const int vel = kV & 7;

  const long krow0_base = (long)chunk0 - WW;   // key window is per CHUNK
  const int t0 = (c == 0) ? 8 : 0;
  const int tN = (c == NCC-1) ? 16 : 24;

  uint4 rkh, rkl, rvh, rvl;
  {
    const long kr = krow0_base + (long)t0*32;
    const size_t offK = (size_t)(kr + kK) * EE + colh + dK;
    const size_t offV = (size_t)(kr + kV) * EE + colh + dV;
    rkh = *(const uint4*)(Kh_g + offK); rkl = *(const uint4*)(Kl_g + offK);
    rvh = *(const uint4*)(Vh_g + offV); rvl = *(const uint4*)(Vl_g + offV);
  }

  for (int tt = t0; tt < tN; ++tt) {
    __syncthreads();   // all waves done reading previous tile's Kf/Vt
    *(uint4*)&Kf[0][wid*512 + lane*8] = rkh;
    *(uint4*)&Kf[1][wid*512 + lane*8] = rkl;
    {
      const unsigned hw[4] = {rvh.x, rvh.y, rvh.z, rvh.w};
      const unsigned lw[4] = {rvl.x, rvl.y, rvl.z, rvl.w};
      #pragma unroll
      for (int t = 0; t < 8; ++t) {
        const int ii = C0*8 + ((t ^ swW) << 3) + vel;
        Vt[0][ii] = (unsigned short)(hw[t >> 1] >> ((t & 1) * 16));
        Vt[1][ii] = (unsigned short)(lw[t >> 1] >> ((t & 1) * 16));
      }
    }
    __syncthreads();   // tile ready

    if (tt + 1 < tN) {   // issue next tile's loads early (hide HBM latency)
      const long kr = krow0_base + (long)(tt+1)*32;
      const size_t offK = (size_t)(kr + kK) * EE + colh + dK;
      const size_t offV = (size_t)(kr + kV) * EE + colh + dV;
      rkh = *(const uint4*)(Kh_g + offK); rkl = *(const uint4*)(Kl_g + offK);
      rvh = *(const uint4*)(Vh_g + offV); rvl = *(const uint4*)(Vl_g + offV);
    }

    // K A-frags: contiguous wave-wide ds_read_b128
    bf16x8 kfh[2][2], kfl[2][2];
    #pragma unroll
    for (int f = 0; f < 4; ++f) {
      const int o = f*512 + lane*8;
      kfh[f & 1][f >> 1] = *(const bf16x8*)&Kf[0][o];
      kfl[f & 1][f >> 1] = *(const bf16x8*)&Kf[1][o];
    }

    // V^T A-frags: contiguous b128 with matching XOR chunk swizzle.
    bf16x8 vfh[4], vfl[4];
    #pragma unroll
    for (int ds = 0; ds < 4; ++ds) {
      const int rch = ds*64 + g*16 + lq;
      const int rsw = (((rch >> 6) & 1) << 2) | (((rch >> 4) & 1) << 1) | ((rch >> 3) & 1);
      vfh[ds] = *(const bf16x8*)&Vt[0][(rch ^ rsw) * 8];
      vfl[ds] = *(const bf16x8*)&Vt[1][(rch ^ rsw) * 8];
    }

    #pragma unroll
    for (int s = 0; s < 2; ++s) {
      // ---- QK^T (3-pass split), D: col q = lane&15, key = g*4 + reg ----
      f32x4 ac0 = (f32x4){0.f,0.f,0.f,0.f}, ac1 = (f32x4){0.f,0.f,0.f,0.f};
      #pragma unroll
      for (int ch = 0; ch < 2; ++ch) {
        ac0 = __builtin_amdgcn_mfma_f32_16x16x32_bf16(kfh[0][ch], qfh[s][ch], ac0, 0,0,0);
        ac0 = __builtin_amdgcn_mfma_f32_16x16x32_bf16(kfh[0][ch], qfl[s][ch], ac0, 0,0,0);
        ac0 = __builtin_amdgcn_mfma_f32_16x16x32_bf16(kfl[0][ch], qfh[s][ch], ac0, 0,0,0);
        ac1 = __builtin_amdgcn_mfma_f32_16x16x32_bf16(kfh[1][ch], qfh[s][ch], ac1, 0,0,0);
        ac1 = __builtin_amdgcn_mfma_f32_16x16x32_bf16(kfh[1][ch], qfl[s][ch], ac1, 0,0,0);
        ac1 = __builtin_amdgcn_mfma_f32_16x16x32_bf16(kfl[1][ch], qfh[s][ch], ac1, 0,0,0);
      }

      // ---- online softmax (per q-column, reduce over the 4 g-lanes) ----
      float tmax = fmaxf(fmaxf(fmaxf(ac0[0],ac0[1]), fmaxf(ac0[2],ac0[3])),
                         fmaxf(fmaxf(ac1[0],ac1[1]), fmaxf(ac1[2],ac1[3])));
      tmax = fmaxf(tmax, __shfl_xor(tmax, 16));
      tmax = fmaxf(tmax, __shfl_xor(tmax, 32));
      const float mo = m[s];
      const float mn = fmaxf(mo, tmax);
      m[s] = mn;
      const float sc = __expf(mo - mn);   // exp(-1e30 - x) == 0
      float pv[8];
      #pragma unroll
      for (int r = 0; r < 4; ++r) { pv[r] = __expf(ac0[r] - mn); pv[4+r] = __expf(ac1[r] - mn); }
      float ps = 0.f;
      #pragma unroll
      for (int r = 0; r < 8; ++r) ps += pv[r];
      lsum[s] = lsum[s] * sc + ps;
      #pragma unroll
      for (int ds = 0; ds < 4; ++ds) Oa[ds][s] *= sc;

      // ---- pack P hi/lo, route via native-u64 LDS scratch ----
      unsigned hb[8], lb[8];
      #pragma unroll
      for (int r = 0; r < 8; ++r) {
        hb[r] = bf16rne(pv[r]);
        const float rr = pv[r] - __uint_as_float(hb[r] << 16);
        lb[r] = bf16rne(rr);
      }
      const int pq = (g >> 1)*32 + lq*2 + (g & 1);   // u64 index; *4 = short idx
      Pscr[wid][pq]            = pack64(hb[0],hb[1],hb[2],hb[3]);
      Pscr[wid][pq + 64]       = pack64(hb[4],hb[5],hb[6],hb[7]);
      Pscr[wid][128 + pq]      = pack64(lb[0],lb[1],lb[2],lb[3]);
      Pscr[wid][128 + pq + 64] = pack64(lb[4],lb[5],lb[6],lb[7]);
      asm volatile("" ::: "memory");   // compiler fence: writes before reads
      union U8 { unsigned long long q[2]; bf16x8 v; };
      U8 uh, ul;
      uh.q[0] = Pscr[wid][lane*2];       uh.q[1] = Pscr[wid][lane*2 + 1];
      ul.q[0] = Pscr[wid][128 + lane*2]; ul.q[1] = Pscr[wid][128 + lane*2 + 1];
      const bf16x8 pbh = uh.v;
      const bf16x8 pbl = ul.v;

      // ---- PV (3-pass split): O^T[d][q] += V^T · P^T ----
      #pragma unroll
      for (int ds = 0; ds < 4; ++ds) {
        Oa[ds][s] = __builtin_amdgcn_mfma_f32_16x16x32_bf16(vfh[ds], pbh, Oa[ds][s], 0,0,0);
        Oa[ds][s] = __builtin_amdgcn_mfma_f32_16x16x32_bf16(vfl[ds], pbh, Oa[ds][s], 0,0,0);
        Oa[ds][s] = __builtin_amdgcn_mfma_f32_16x16x32_bf16(vfh[ds], pbl, Oa[ds][s], 0,0,0);
      }
    }
  }

  // ---- epilogue: fold zero-pad keys, normalize, store ----
  #pragma unroll
  for (int s = 0; s < 2; ++s) {
    float ls = lsum[s];
    ls += __shfl_xor(ls, 16);
    ls += __shfl_xor(ls, 32);
    const int x = qh*128 + wid*32 + s*16 + lq;   // row within the chunk
    const float nz = (c == 0) ? (float)x
                   : ((c == NCC-1) ? (float)(WW - 1 - x) : 0.f);
    ls += nz * __expf(0.f - m[s]);
    const float inv = 1.f / ls;
    float* op = Og + (chunk0 + x) * EE + colh;
    #pragma unroll
    for (int ds = 0; ds < 4; ++ds) {
      float4 r;
      r.x = Oa[ds][s][0]*inv; r.y = Oa[ds][s][1]*inv;
      r.z = Oa[ds][s][2]*inv; r.w = Oa[ds][s][3]*inv;
      *(float4*)(op + ds*16 + g*4) = r;
    }
  }
}

extern "C" void kernel_launch(void* const* d_in, const int* in_sizes, int n_in,
                              void* d_out, int out_size, void* d_ws, size_t ws_size,
                              hipStream_t stream) {
    const float* hs = (const float*)d_in[0];
    const float* Wq = (const float*)d_in[1];
    const float* bq = (const float*)d_in[2];
    const float* Wk = (const float*)d_in[3];
    const float* bk = (const float*)d_in[4];
    const float* Wv = (const float*)d_in[5];
    const float* bv = (const float*)d_in[6];
    float* out = (float*)d_out;

    const size_t mat  = (size_t)MTOT * EE;   // 8388608
    const size_t wmat = (size_t)EE * EE;     // 1048576

    unsigned short* w = (unsigned short*)d_ws;
    unsigned short* Ahi = w;            unsigned short* Alo = Ahi + mat;
    unsigned short* Wqh = Alo + mat;    unsigned short* Wql = Wqh + wmat;
    unsigned short* Wkh = Wql + wmat;   unsigned short* Wkl = Wkh + wmat;
    unsigned short* Wvh = Wkl + wmat;   unsigned short* Wvl = Wvh + wmat;
    unsigned short* Qhb = Wvl + wmat;   unsigned short* Qlb = Qhb + mat;
    unsigned short* Khb = Qlb + mat;    unsigned short* Klb = Khb + mat;
    unsigned short* Vhb = Klb + mat;    unsigned short* Vlb = Vhb + mat;
    // total ws: (8*mat + 6*wmat)*2B = 140 MB

    // one dispatch for all four splits: 8192 (hs) + 3*1024 (weights) blocks
    split_all<<<8192 + 3*1024, 256, 0, stream>>>(
        hs, Wq, Wk, Wv, Ahi, Alo, Wqh, Wql, Wkh, Wkl, Wvh, Wvl);

    ProjArgs pq{Wqh, Wql, bq, Qhb, Qlb, 0.125f};   // 1/sqrt(64)
    ProjArgs pk{Wkh, Wkl, bk, Khb, Klb, 1.0f};
    ProjArgs pv{Wvh, Wvl, bv, Vhb, Vlb, 1.0f};
    dim3 g(MTOT/256, EE/128, 3);
    mfma_proj<<<g, 512, 0, stream>>>(Ahi, Alo, pq, pk, pv);

    dim3 ga(NCC, HH, BB*2);
    attn_mfma<<<ga, 256, 0, stream>>>(Qhb, Qlb, Khb, Klb, Vhb, Vlb, out);
}

// Round 13
// 304.061 us; speedup vs baseline: 1.3786x; 1.3786x over previous
//
#include <hip/hip_runtime.h>
#include <math.h>

#define BB  2
#define SS  4096
#define EE  1024
#define HH  16
#define DD  64
#define WW  256
#define NCC 16   // SS / WW
#define MTOT (BB*SS)   // 8192

typedef __attribute__((ext_vector_type(4))) float f32x4;
typedef __attribute__((ext_vector_type(8))) short bf16x8;

// ---------------------------------------------------------------------------
// async global->LDS, 16B per lane. LDS dest must be wave-uniform base
// (+lane*16 is applied by HW); global src is per-lane.
// ---------------------------------------------------------------------------
__device__ __forceinline__ void gl_lds16(const void* g, void* l) {
  __builtin_amdgcn_global_load_lds(
      (const __attribute__((address_space(1))) unsigned int*)g,
      (__attribute__((address_space(3))) unsigned int*)l,
      16, 0, 0);
}

__device__ __forceinline__ unsigned bf16rne(float f) {
  unsigned u = __float_as_uint(f);
  return (u + (((u >> 16) & 1u) + 0x7fffu)) >> 16;
}

__device__ __forceinline__ unsigned long long pack64(unsigned a, unsigned b,
                                                     unsigned c2, unsigned d) {
  return (unsigned long long)(a | (b << 16)) |
         ((unsigned long long)(c2 | (d << 16)) << 32);
}

// ---------------------------------------------------------------------------
// Fused split pass: fp32 -> bf16 hi (truncated) + bf16 lo (RNE of residual)
// for hidden_states and the three weight matrices in ONE dispatch.
// ---------------------------------------------------------------------------
__global__ __launch_bounds__(256) void split_all(
    const float* __restrict__ hs, const float* __restrict__ Wq,
    const float* __restrict__ Wk, const float* __restrict__ Wv,
    unsigned short* __restrict__ Ahi, unsigned short* __restrict__ Alo,
    unsigned short* __restrict__ Wqh, unsigned short* __restrict__ Wql,
    unsigned short* __restrict__ Wkh, unsigned short* __restrict__ Wkl,
    unsigned short* __restrict__ Wvh, unsigned short* __restrict__ Wvl)
{
  const int bx = blockIdx.x;
  const float* src; unsigned short *hi, *lo; size_t blk;
  if (bx < 8192)       { src = hs; hi = Ahi; lo = Alo; blk = bx; }
  else if (bx < 9216)  { src = Wq; hi = Wqh; lo = Wql; blk = bx - 8192; }
  else if (bx < 10240) { src = Wk; hi = Wkh; lo = Wkl; blk = bx - 9216; }
  else                 { src = Wv; hi = Wvh; lo = Wvl; blk = bx - 10240; }

  const size_t i = blk * 256 + threadIdx.x;
  const float4 v = ((const float4*)src)[i];
  float f[4] = {v.x, v.y, v.z, v.w};
  unsigned short h[4], l[4];
  #pragma unroll
  for (int j = 0; j < 4; ++j) {
    unsigned u  = __float_as_uint(f[j]);
    unsigned uh = u & 0xFFFF0000u;
    h[j] = (unsigned short)(uh >> 16);
    float r = f[j] - __uint_as_float(uh);
    unsigned ur = __float_as_uint(r);
    ur += ((ur >> 16) & 1u) + 0x7FFFu;
    l[j] = (unsigned short)(ur >> 16);
  }
  *(ushort4*)&hi[4*i] = make_ushort4(h[0], h[1], h[2], h[3]);
  *(ushort4*)&lo[4*i] = make_ushort4(l[0], l[1], l[2], l[3]);
}

// ---------------------------------------------------------------------------
// bf16x3-split MFMA projection GEMM (exact R11 state: best measured 192 us).
// 256x128 tile, 512 threads, 3-deep LDS pipeline (144 KB), pipelined
// fragment reads with counted lgkmcnt, vmcnt steady at 12.
// ---------------------------------------------------------------------------
struct ProjArgs {
  const unsigned short* Wh;
  const unsigned short* Wl;
  const float* bias;
  unsigned short* outHi;
  unsigned short* outLo;
  float scale;
};

__global__ __launch_bounds__(512) void mfma_proj(
    const unsigned short* __restrict__ Ahi,
    const unsigned short* __restrict__ Alo,
    ProjArgs p0, ProjArgs p1, ProjArgs p2)
{
  __shared__ __align__(16) union {
    unsigned short stage[3][24576];     // 48 KB per buffer (in shorts)
    unsigned short ep[128][136];
  } sh;

  const int tid  = threadIdx.x;
  const int lane = tid & 63;
  const int wid  = tid >> 6;          // 0..7
  const int wr   = wid >> 1;          // 0..3  (M)
  const int wc   = wid & 1;           // 0..1  (N)
  const int m0   = blockIdx.x * 256, n0 = blockIdx.y * 128;
  const ProjArgs P = (blockIdx.z == 0) ? p0 : ((blockIdx.z == 1) ? p1 : p2);

  const int qA0 = tid, qA1 = 512 + tid;
  const int rowA0 = ((qA0 >> 5) << 3) | (qA0 & 7), kcA0 = (qA0 >> 3) & 3;
  const int rowA1 = ((qA1 >> 5) << 3) | (qA1 & 7), kcA1 = (qA1 >> 3) & 3;
  const int rowB  = rowA0, kcB = kcA0;

  const size_t aoff0 = (size_t)(m0 + rowA0) * 2048 + (size_t)(kcA0 * 16);
  const size_t aoff1 = (size_t)(m0 + rowA1) * 2048 + (size_t)(kcA1 * 16);
  const size_t boff  = (size_t)(n0 + rowB)  * 2048 + (size_t)(kcB  * 16);

  const int dstA0 = wid * 1024;
  const int dstA1 = 8192 + wid * 1024;
  const int dstB  = wid * 1024;

  const char* gAh = (const char*)Ahi;
  const char* gAl = (const char*)Alo;
  const char* gBh = (const char*)P.Wh;
  const char* gBl = (const char*)P.Wl;

  const int fr = lane & 15;
  const int kc = lane >> 4;
  int a_o[4], b_o[4];
  #pragma unroll
  for (int f = 0; f < 4; ++f) {
    int r = wr * 64 + f * 16 + fr;
    a_o[f] = ((r >> 3) << 9) | (kc << 7) | ((r & 7) << 4);
    r = wc * 64 + f * 16 + fr;
    b_o[f] = ((r >> 3) << 9) | (kc << 7) | ((r & 7) << 4);
  }

  f32x4 acc[4][4];
  #pragma unroll
  for (int i = 0; i < 4; ++i)
    #pragma unroll
    for (int j = 0; j < 4; ++j) acc[i][j] = (f32x4){0.f, 0.f, 0.f, 0.f};

  char* const Lp = (char*)&sh.stage[0][0];
  #define PL(b, p) (Lp + ((b) * 49152 + (p)))

  #define STAGE(buf, ks) { const size_t kb = (size_t)(ks) * 64; \
    gl_lds16(gAh + aoff0 + kb, PL(buf,0)     + dstA0); \
    gl_lds16(gAh + aoff1 + kb, PL(buf,0)     + dstA1); \
    gl_lds16(gAl + aoff0 + kb, PL(buf,16384) + dstA0); \
    gl_lds16(gAl + aoff1 + kb, PL(buf,16384) + dstA1); \
    gl_lds16(gBh + boff  + kb, PL(buf,32768) + dstB); \
    gl_lds16(gBl + boff  + kb, PL(buf,40960) + dstB); }

  bf16x8 ah0[4], bh0[4], ah1[4], bh1[4];
  bf16x8 al[4], bl[4];

  #define RD_C1(AH, BH, buf) { \
    _Pragma("unroll") \
    for (int f = 0; f < 4; ++f) { \
      AH[f] = *(const bf16x8*)(PL(buf,0)     + a_o[f]); \
      BH[f] = *(const bf16x8*)(PL(buf,32768) + b_o[f]); \
    } }
  #define RD_C2(buf) { \
    _Pragma("unroll") \
    for (int f = 0; f < 4; ++f) { \
      al[f] = *(const bf16x8*)(PL(buf,16384) + a_o[f]); \
      bl[f] = *(const bf16x8*)(PL(buf,40960) + b_o[f]); \
    } }

  #define MM16(AA, BBV) { \
    _Pragma("unroll") \
    for (int i = 0; i < 4; ++i) \
      _Pragma("unroll") \
      for (int j = 0; j < 4; ++j) \
        acc[i][j] = __builtin_amdgcn_mfma_f32_16x16x32_bf16(AA[i], BBV[j], acc[i][j], 0,0,0); }

  #define ITER(KS, B, BN, AHc, BHc, AHn, BHn, VM, DOSTAGE, DONEXT) { \
    RD_C2(B); \
    __builtin_amdgcn_sched_barrier(0); \
    asm volatile("s_waitcnt lgkmcnt(8)" ::: "memory"); \
    __builtin_amdgcn_sched_barrier(0); \
    __builtin_amdgcn_s_setprio(1); \
    MM16(AHc, BHc); \
    __builtin_amdgcn_s_setprio(0); \
    __builtin_amdgcn_sched_barrier(0); \
    asm volatile("s_waitcnt lgkmcnt(0)" ::: "memory"); \
    __builtin_amdgcn_sched_barrier(0); \
    __builtin_amdgcn_s_barrier(); \
    if (DOSTAGE) STAGE(B, (KS)+3); \
    if (VM == 12)     { asm volatile("s_waitcnt vmcnt(12)" ::: "memory"); } \
    else if (VM == 6) { asm volatile("s_waitcnt vmcnt(6)"  ::: "memory"); } \
    else if (VM == 0) { asm volatile("s_waitcnt vmcnt(0)"  ::: "memory"); } \
    if (VM >= 0) { __builtin_amdgcn_sched_barrier(0); __builtin_amdgcn_s_barrier(); } \
    if (DONEXT) RD_C1(AHn, BHn, BN); \
    __builtin_amdgcn_s_setprio(1); \
    MM16(AHc, bl); \
    MM16(al, BHc); \
    __builtin_amdgcn_s_setprio(0); \
  }

  STAGE(0, 0);
  STAGE(1, 1);
  STAGE(2, 2);
  asm volatile("s_waitcnt vmcnt(12)" ::: "memory");
  __builtin_amdgcn_sched_barrier(0);
  __builtin_amdgcn_s_barrier();
  RD_C1(ah0, bh0, 0);

  for (int kk = 0; kk < 24; kk += 6) {
    ITER(kk+0, 0, 1, ah0, bh0, ah1, bh1, 12, 1, 1);
    ITER(kk+1, 1, 2, ah1, bh1, ah0, bh0, 12, 1, 1);
    ITER(kk+2, 2, 0, ah0, bh0, ah1, bh1, 12, 1, 1);
    ITER(kk+3, 0, 1, ah1, bh1, ah0, bh0, 12, 1, 1);
    ITER(kk+4, 1, 2, ah0, bh0, ah1, bh1, 12, 1, 1);
    ITER(kk+5, 2, 0, ah1, bh1, ah0, bh0, 12, 1, 1);
  }
  ITER(24, 0, 1, ah0, bh0, ah1, bh1, 12, 1, 1);
  ITER(25, 1, 2, ah1, bh1, ah0, bh0, 12, 1, 1);
  ITER(26, 2, 0, ah0, bh0, ah1, bh1, 12, 1, 1);
  ITER(27, 0, 1, ah1, bh1, ah0, bh0, 12, 1, 1);
  ITER(28, 1, 2, ah0, bh0, ah1, bh1, 12, 1, 1);
  ITER(29, 2, 0, ah1, bh1, ah0, bh0,  6, 0, 1);
  ITER(30, 0, 1, ah0, bh0, ah1, bh1,  0, 0, 1);
  ITER(31, 1, 2, ah1, bh1, ah0, bh0, -1, 0, 0);
  #undef PL
  #undef STAGE
  #undef RD_C1
  #undef RD_C2
  #undef MM16
  #undef ITER

  const int r4 = (lane >> 4) << 2;
  #pragma unroll
  for (int hh = 0; hh < 2; ++hh) {
    #pragma unroll
    for (int plane = 0; plane < 2; ++plane) {
      __syncthreads();
      if ((wr >> 1) == hh) {
        #pragma unroll
        for (int j = 0; j < 4; ++j) {
          const int col_l = wc*64 + j*16 + fr;
          const float bv = P.bias[n0 + col_l];
          #pragma unroll
          for (int i = 0; i < 4; ++i) {
            const int rl0 = (wr & 1)*64 + i*16 + r4;
            #pragma unroll
            for (int v = 0; v < 4; ++v) {
              const float val = (acc[i][j][v] + bv) * P.scale;
              const unsigned u = __float_as_uint(val);
              unsigned sv;
              if (plane == 0) { sv = u >> 16; }
              else {
                const float rres = val - __uint_as_float(u & 0xFFFF0000u);
                unsigned ur = __float_as_uint(rres);
                ur += ((ur >> 16) & 1u) + 0x7FFFu; sv = ur >> 16;
              }
              const int rl = rl0 + v;
              sh.ep[rl][(((col_l >> 3) ^ (rl & 7)) << 3) + (col_l & 7)] =
                  (unsigned short)sv;
            }
          }
        }
      }
      __syncthreads();
      unsigned short* const OUT = plane ? P.outLo : P.outHi;
      #pragma unroll
      for (int u2 = 0; u2 < 4; ++u2) {
        const int chunk = u2 * 512 + tid;
        const int rr = chunk >> 4, c16 = chunk & 15;
        const bf16x8 vv = *(const bf16x8*)&sh.ep[rr][(c16 ^ (rr & 7)) << 3];
        *(bf16x8*)&OUT[(size_t)(m0 + hh*128 + rr) * EE + n0 + c16*8] = vv;
      }
    }
  }
}

// ---------------------------------------------------------------------------
// MFMA fused no-overlap sliding-chunk attention.
// R13: 1D grid + XCD-chunked bijective swizzle (T1: each XCD owns 8 heads x
// full chunk sweep -> adjacent chunks' shared K/V windows become L2 hits)
// and s_setprio around QK^T / PV MFMA clusters (T5: attn regime, +4-7%).
// Block math identical to passing R11 -> bit-identical numerics.
// ---------------------------------------------------------------------------
__global__ __launch_bounds__(256) void attn_mfma(
    const unsigned short* __restrict__ Qh_g, const unsigned short* __restrict__ Ql_g,
    const unsigned short* __restrict__ Kh_g, const unsigned short* __restrict__ Kl_g,
    const unsigned short* __restrict__ Vh_g, const unsigned short* __restrict__ Vl_g,
    float* __restrict__ Og)
{
  __shared__ __align__(16) unsigned short Kf[2][2048];   // [plane][frag-linear]
  __shared__ __align__(16) unsigned short Vt[2][2048];   // [plane][V^T frag-linear, swz]
  __shared__ unsigned long long Pscr[4][256];            // per wave: hi[0:128) lo[128:256)

  // XCD-chunked bijective swizzle: 1024 wgs, 1024%8==0 -> chunk size 128.
  // Within a chunk, c varies fastest -> one XCD sweeps chunks for 8 heads.
  const int swz = (blockIdx.x & 7) * 128 + (blockIdx.x >> 3);
  const int c  = swz & (NCC - 1);
  const int h  = (swz >> 4) & (HH - 1);
  const int bz = swz >> 8;                     // 0..3
  const int b = bz >> 1, qh = bz & 1;          // batch, q-half of the chunk
  const int tid = threadIdx.x;
  const int lane = tid & 63, wid = tid >> 6;
  const int g = lane >> 4, lq = lane & 15;

  const size_t chunk0 = (size_t)(b * NCC + c) * WW;   // chunk row start
  const size_t qrow0  = chunk0 + (size_t)qh * 128;    // this block's q rows
  const int colh = h * DD;

  // ---- Q B-frags (col q = lane&15, k-elems d = g*8..), 2 subtiles/wave ----
  bf16x8 qfh[2][2], qfl[2][2];
  #pragma unroll
  for (int s = 0; s < 2; ++s)
    #pragma unroll
    for (int ch = 0; ch < 2; ++ch) {
      const size_t off = (qrow0 + wid*32 + s*16 + lq) * EE + colh + ch*32 + g*8;
      qfh[s][ch] = *(const bf16x8*)(Qh_g + off);
      qfl[s][ch] = *(const bf16x8*)(Ql_g + off);
    }

  f32x4 Oa[4][2];   // [d-subtile][q-subtile]
  #pragma unroll
  for (int i = 0; i < 4; ++i)
    #pragma unroll
    for (int j = 0; j < 2; ++j) Oa[i][j] = (f32x4){0.f, 0.f, 0.f, 0.f};
  float m[2], lsum[2];
  #pragma unroll
  for (int s = 0; s < 2; ++s) { m[s] = -1e30f; lsum[s] = 0.f; }

  // K staging: wave wid stages A-frag f=wid (kh=wid&1, ch=wid>>1), frag-linear.
  const int kK = 16*(wid & 1) + lq;
  const int dK = 32*(wid >> 1) + g*8;
  // V staging: thread holds V[kV][dV..dV+7]; scattered to V^T frag-linear.
  const int stv = tid >> 5, idxv = tid & 31;
  const int kV = 16*(stv >> 2) + (idxv >> 1);
  const int dV = 16*(stv & 3) + 8*(idxv & 1);
  const int C0  = ((dV >> 4) << 6) | ((kV >> 3) << 4) | (dV & 15);
  const int swW = (((dV >> 4) & 1) << 2) | (((kV >> 3) & 1) << 1) | ((dV >> 3) & 1);
  const int vel = kV & 7;

  const long krow0_base = (long)chunk0 - WW;   // key window is per CHUNK
  const int t0 = (c == 0) ? 8 : 0;
  const int tN = (c == NCC-1) ? 16 : 24;

  uint4 rkh, rkl, rvh, rvl;
  {
    const long kr = krow0_base + (long)t0*32;
    const size_t offK = (size_t)(kr + kK) * EE + colh + dK;
    const size_t offV = (size_t)(kr + kV) * EE + colh + dV;
    rkh = *(const uint4*)(Kh_g + offK); rkl = *(const uint4*)(Kl_g + offK);
    rvh = *(const uint4*)(Vh_g + offV); rvl = *(const uint4*)(Vl_g + offV);
  }

  for (int tt = t0; tt < tN; ++tt) {
    __syncthreads();   // all waves done reading previous tile's Kf/Vt
    *(uint4*)&Kf[0][wid*512 + lane*8] = rkh;
    *(uint4*)&Kf[1][wid*512 + lane*8] = rkl;
    {
      const unsigned hw[4] = {rvh.x, rvh.y, rvh.z, rvh.w};
      const unsigned lw[4] = {rvl.x, rvl.y, rvl.z, rvl.w};
      #pragma unroll
      for (int t = 0; t < 8; ++t) {
        const int ii = C0*8 + ((t ^ swW) << 3) + vel;
        Vt[0][ii] = (unsigned short)(hw[t >> 1] >> ((t & 1) * 16));
        Vt[1][ii] = (unsigned short)(lw[t >> 1] >> ((t & 1) * 16));
      }
    }
    __syncthreads();   // tile ready

    if (tt + 1 < tN) {   // issue next tile's loads early (hide HBM latency)
      const long kr = krow0_base + (long)(tt+1)*32;
      const size_t offK = (size_t)(kr + kK) * EE + colh + dK;
      const size_t offV = (size_t)(kr + kV) * EE + colh + dV;
      rkh = *(const uint4*)(Kh_g + offK); rkl = *(const uint4*)(Kl_g + offK);
      rvh = *(const uint4*)(Vh_g + offV); rvl = *(const uint4*)(Vl_g + offV);
    }

    // K A-frags: contiguous wave-wide ds_read_b128
    bf16x8 kfh[2][2], kfl[2][2];
    #pragma unroll
    for (int f = 0; f < 4; ++f) {
      const int o = f*512 + lane*8;
      kfh[f & 1][f >> 1] = *(const bf16x8*)&Kf[0][o];
      kfl[f & 1][f >> 1] = *(const bf16x8*)&Kf[1][o];
    }

    // V^T A-frags: contiguous b128 with matching XOR chunk swizzle.
    bf16x8 vfh[4], vfl[4];
    #pragma unroll
    for (int ds = 0; ds < 4; ++ds) {
      const int rch = ds*64 + g*16 + lq;
      const int rsw = (((rch >> 6) & 1) << 2) | (((rch >> 4) & 1) << 1) | ((rch >> 3) & 1);
      vfh[ds] = *(const bf16x8*)&Vt[0][(rch ^ rsw) * 8];
      vfl[ds] = *(const bf16x8*)&Vt[1][(rch ^ rsw) * 8];
    }

    #pragma unroll
    for (int s = 0; s < 2; ++s) {
      // ---- QK^T (3-pass split), D: col q = lane&15, key = g*4 + reg ----
      f32x4 ac0 = (f32x4){0.f,0.f,0.f,0.f}, ac1 = (f32x4){0.f,0.f,0.f,0.f};
      __builtin_amdgcn_s_setprio(1);
      #pragma unroll
      for (int ch = 0; ch < 2; ++ch) {
        ac0 = __builtin_amdgcn_mfma_f32_16x16x32_bf16(kfh[0][ch], qfh[s][ch], ac0, 0,0,0);
        ac0 = __builtin_amdgcn_mfma_f32_16x16x32_bf16(kfh[0][ch], qfl[s][ch], ac0, 0,0,0);
        ac0 = __builtin_amdgcn_mfma_f32_16x16x32_bf16(kfl[0][ch], qfh[s][ch], ac0, 0,0,0);
        ac1 = __builtin_amdgcn_mfma_f32_16x16x32_bf16(kfh[1][ch], qfh[s][ch], ac1, 0,0,0);
        ac1 = __builtin_amdgcn_mfma_f32_16x16x32_bf16(kfh[1][ch], qfl[s][ch], ac1, 0,0,0);
        ac1 = __builtin_amdgcn_mfma_f32_16x16x32_bf16(kfl[1][ch], qfh[s][ch], ac1, 0,0,0);
      }
      __builtin_amdgcn_s_setprio(0);

      // ---- online softmax (per q-column, reduce over the 4 g-lanes) ----
      float tmax = fmaxf(fmaxf(fmaxf(ac0[0],ac0[1]), fmaxf(ac0[2],ac0[3])),
                         fmaxf(fmaxf(ac1[0],ac1[1]), fmaxf(ac1[2],ac1[3])));
      tmax = fmaxf(tmax, __shfl_xor(tmax, 16));
      tmax = fmaxf(tmax, __shfl_xor(tmax, 32));
      const float mo = m[s];
      const float mn = fmaxf(mo, tmax);
      m[s] = mn;
      const float sc = __expf(mo - mn);   // exp(-1e30 - x) == 0
      float pv[8];
      #pragma unroll
      for (int r = 0; r < 4; ++r) { pv[r] = __expf(ac0[r] - mn); pv[4+r] = __expf(ac1[r] - mn); }
      float ps = 0.f;
      #pragma unroll
      for (int r = 0; r < 8; ++r) ps += pv[r];
      lsum[s] = lsum[s] * sc + ps;
      #pragma unroll
      for (int ds = 0; ds < 4; ++ds) Oa[ds][s] *= sc;

      // ---- pack P hi/lo, route via native-u64 LDS scratch ----
      unsigned hb[8], lb[8];
      #pragma unroll
      for (int r = 0; r < 8; ++r) {
        hb[r] = bf16rne(pv[r]);
        const float rr = pv[r] - __uint_as_float(hb[r] << 16);
        lb[r] = bf16rne(rr);
      }
      const int pq = (g >> 1)*32 + lq*2 + (g & 1);   // u64 index; *4 = short idx
      Pscr[wid][pq]            = pack64(hb[0],hb[1],hb[2],hb[3]);
      Pscr[wid][pq + 64]       = pack64(hb[4],hb[5],hb[6],hb[7]);
      Pscr[wid][128 + pq]      = pack64(lb[0],lb[1],lb[2],lb[3]);
      Pscr[wid][128 + pq + 64] = pack64(lb[4],lb[5],lb[6],lb[7]);
      asm volatile("" ::: "memory");   // compiler fence: writes before reads
      union U8 { unsigned long long q[2]; bf16x8 v; };
      U8 uh, ul;
      uh.q[0] = Pscr[wid][lane*2];       uh.q[1] = Pscr[wid][lane*2 + 1];
      ul.q[0] = Pscr[wid][128 + lane*2]; ul.q[1] = Pscr[wid][128 + lane*2 + 1];
      const bf16x8 pbh = uh.v;
      const bf16x8 pbl = ul.v;

      // ---- PV (3-pass split): O^T[d][q] += V^T · P^T ----
      __builtin_amdgcn_s_setprio(1);
      #pragma unroll
      for (int ds = 0; ds < 4; ++ds) {
        Oa[ds][s] = __builtin_amdgcn_mfma_f32_16x16x32_bf16(vfh[ds], pbh, Oa[ds][s], 0,0,0);
        Oa[ds][s] = __builtin_amdgcn_mfma_f32_16x16x32_bf16(vfl[ds], pbh, Oa[ds][s], 0,0,0);
        Oa[ds][s] = __builtin_amdgcn_mfma_f32_16x16x32_bf16(vfh[ds], pbl, Oa[ds][s], 0,0,0);
      }
      __builtin_amdgcn_s_setprio(0);
    }
  }

  // ---- epilogue: fold zero-pad keys, normalize, store ----
  #pragma unroll
  for (int s = 0; s < 2; ++s) {
    float ls = lsum[s];
    ls += __shfl_xor(ls, 16);
    ls += __shfl_xor(ls, 32);
    const int x = qh*128 + wid*32 + s*16 + lq;   // row within the chunk
    const float nz = (c == 0) ? (float)x
                   : ((c == NCC-1) ? (float)(WW - 1 - x) : 0.f);
    ls += nz * __expf(0.f - m[s]);
    const float inv = 1.f / ls;
    float* op = Og + (chunk0 + x) * EE + colh;
    #pragma unroll
    for (int ds = 0; ds < 4; ++ds) {
      float4 r;
      r.x = Oa[ds][s][0]*inv; r.y = Oa[ds][s][1]*inv;
      r.z = Oa[ds][s][2]*inv; r.w = Oa[ds][s][3]*inv;
      *(float4*)(op + ds*16 + g*4) = r;
    }
  }
}

extern "C" void kernel_launch(void* const* d_in, const int* in_sizes, int n_in,
                              void* d_out, int out_size, void* d_ws, size_t ws_size,
                              hipStream_t stream) {
    const float* hs = (const float*)d_in[0];
    const float* Wq = (const float*)d_in[1];
    const float* bq = (const float*)d_in[2];
    const float* Wk = (const float*)d_in[3];
    const float* bk = (const float*)d_in[4];
    const float* Wv = (const float*)d_in[5];
    const float* bv = (const float*)d_in[6];
    float* out = (float*)d_out;

    const size_t mat  = (size_t)MTOT * EE;   // 8388608
    const size_t wmat = (size_t)EE * EE;     // 1048576

    unsigned short* w = (unsigned short*)d_ws;
    unsigned short* Ahi = w;            unsigned short* Alo = Ahi + mat;
    unsigned short* Wqh = Alo + mat;    unsigned short* Wql = Wqh + wmat;
    unsigned short* Wkh = Wql + wmat;   unsigned short* Wkl = Wkh + wmat;
    unsigned short* Wvh = Wkl + wmat;   unsigned short* Wvl = Wvh + wmat;
    unsigned short* Qhb = Wvl + wmat;   unsigned short* Qlb = Qhb + mat;
    unsigned short* Khb = Qlb + mat;    unsigned short* Klb = Khb + mat;
    unsigned short* Vhb = Klb + mat;    unsigned short* Vlb = Vhb + mat;
    // total ws: (8*mat + 6*wmat)*2B = 140 MB

    // one dispatch for all four splits: 8192 (hs) + 3*1024 (weights) blocks
    split_all<<<8192 + 3*1024, 256, 0, stream>>>(
        hs, Wq, Wk, Wv, Ahi, Alo, Wqh, Wql, Wkh, Wkl, Wvh, Wvl);

    ProjArgs pq{Wqh, Wql, bq, Qhb, Qlb, 0.125f};   // 1/sqrt(64)
    ProjArgs pk{Wkh, Wkl, bk, Khb, Klb, 1.0f};
    ProjArgs pv{Wvh, Wvl, bv, Vhb, Vlb, 1.0f};
    dim3 g(MTOT/256, EE/128, 3);
    mfma_proj<<<g, 512, 0, stream>>>(Ahi, Alo, pq, pk, pv);

    // attn: 1D grid with XCD-chunked swizzle (1024 = 8 XCD-chunks x 128)
    attn_mfma<<<NCC*HH*BB*2, 256, 0, stream>>>(Qhb, Qlb, Khb, Klb, Vhb, Vlb, out);
}

// Round 14
// 296.278 us; speedup vs baseline: 1.4148x; 1.0263x over previous
//
#include <hip/hip_runtime.h>
#include <math.h>

#define BB  2
#define SS  4096
#define EE  1024
#define HH  16
#define DD  64
#define WW  256
#define NCC 16   // SS / WW
#define MTOT (BB*SS)   // 8192

typedef __attribute__((ext_vector_type(4))) float f32x4;
typedef __attribute__((ext_vector_type(8))) short bf16x8;

// ---------------------------------------------------------------------------
// async global->LDS, 16B per lane. LDS dest must be wave-uniform base
// (+lane*16 is applied by HW); global src is per-lane.
// ---------------------------------------------------------------------------
__device__ __forceinline__ void gl_lds16(const void* g, void* l) {
  __builtin_amdgcn_global_load_lds(
      (const __attribute__((address_space(1))) unsigned int*)g,
      (__attribute__((address_space(3))) unsigned int*)l,
      16, 0, 0);
}

__device__ __forceinline__ unsigned bf16rne(float f) {
  unsigned u = __float_as_uint(f);
  return (u + (((u >> 16) & 1u) + 0x7fffu)) >> 16;
}

__device__ __forceinline__ unsigned long long pack64(unsigned a, unsigned b,
                                                     unsigned c2, unsigned d) {
  return (unsigned long long)(a | (b << 16)) |
         ((unsigned long long)(c2 | (d << 16)) << 32);
}

// ---------------------------------------------------------------------------
// Fused split pass: fp32 -> bf16 hi (truncated) + bf16 lo (RNE of residual)
// for hidden_states and the three weight matrices in ONE dispatch.
// ---------------------------------------------------------------------------
__global__ __launch_bounds__(256) void split_all(
    const float* __restrict__ hs, const float* __restrict__ Wq,
    const float* __restrict__ Wk, const float* __restrict__ Wv,
    unsigned short* __restrict__ Ahi, unsigned short* __restrict__ Alo,
    unsigned short* __restrict__ Wqh, unsigned short* __restrict__ Wql,
    unsigned short* __restrict__ Wkh, unsigned short* __restrict__ Wkl,
    unsigned short* __restrict__ Wvh, unsigned short* __restrict__ Wvl)
{
  const int bx = blockIdx.x;
  const float* src; unsigned short *hi, *lo; size_t blk;
  if (bx < 8192)       { src = hs; hi = Ahi; lo = Alo; blk = bx; }
  else if (bx < 9216)  { src = Wq; hi = Wqh; lo = Wql; blk = bx - 8192; }
  else if (bx < 10240) { src = Wk; hi = Wkh; lo = Wkl; blk = bx - 9216; }
  else                 { src = Wv; hi = Wvh; lo = Wvl; blk = bx - 10240; }

  const size_t i = blk * 256 + threadIdx.x;
  const float4 v = ((const float4*)src)[i];
  float f[4] = {v.x, v.y, v.z, v.w};
  unsigned short h[4], l[4];
  #pragma unroll
  for (int j = 0; j < 4; ++j) {
    unsigned u  = __float_as_uint(f[j]);
    unsigned uh = u & 0xFFFF0000u;
    h[j] = (unsigned short)(uh >> 16);
    float r = f[j] - __uint_as_float(uh);
    unsigned ur = __float_as_uint(r);
    ur += ((ur >> 16) & 1u) + 0x7FFFu;
    l[j] = (unsigned short)(ur >> 16);
  }
  *(ushort4*)&hi[4*i] = make_ushort4(h[0], h[1], h[2], h[3]);
  *(ushort4*)&lo[4*i] = make_ushort4(l[0], l[1], l[2], l[3]);
}

// ---------------------------------------------------------------------------
// bf16x3-split MFMA projection GEMM (exact R11 state: best measured 192 us).
// ---------------------------------------------------------------------------
struct ProjArgs {
  const unsigned short* Wh;
  const unsigned short* Wl;
  const float* bias;
  unsigned short* outHi;
  unsigned short* outLo;
  float scale;
};

__global__ __launch_bounds__(512) void mfma_proj(
    const unsigned short* __restrict__ Ahi,
    const unsigned short* __restrict__ Alo,
    ProjArgs p0, ProjArgs p1, ProjArgs p2)
{
  __shared__ __align__(16) union {
    unsigned short stage[3][24576];     // 48 KB per buffer (in shorts)
    unsigned short ep[128][136];
  } sh;

  const int tid  = threadIdx.x;
  const int lane = tid & 63;
  const int wid  = tid >> 6;          // 0..7
  const int wr   = wid >> 1;          // 0..3  (M)
  const int wc   = wid & 1;           // 0..1  (N)
  const int m0   = blockIdx.x * 256, n0 = blockIdx.y * 128;
  const ProjArgs P = (blockIdx.z == 0) ? p0 : ((blockIdx.z == 1) ? p1 : p2);

  const int qA0 = tid, qA1 = 512 + tid;
  const int rowA0 = ((qA0 >> 5) << 3) | (qA0 & 7), kcA0 = (qA0 >> 3) & 3;
  const int rowA1 = ((qA1 >> 5) << 3) | (qA1 & 7), kcA1 = (qA1 >> 3) & 3;
  const int rowB  = rowA0, kcB = kcA0;

  const size_t aoff0 = (size_t)(m0 + rowA0) * 2048 + (size_t)(kcA0 * 16);
  const size_t aoff1 = (size_t)(m0 + rowA1) * 2048 + (size_t)(kcA1 * 16);
  const size_t boff  = (size_t)(n0 + rowB)  * 2048 + (size_t)(kcB  * 16);

  const int dstA0 = wid * 1024;
  const int dstA1 = 8192 + wid * 1024;
  const int dstB  = wid * 1024;

  const char* gAh = (const char*)Ahi;
  const char* gAl = (const char*)Alo;
  const char* gBh = (const char*)P.Wh;
  const char* gBl = (const char*)P.Wl;

  const int fr = lane & 15;
  const int kc = lane >> 4;
  int a_o[4], b_o[4];
  #pragma unroll
  for (int f = 0; f < 4; ++f) {
    int r = wr * 64 + f * 16 + fr;
    a_o[f] = ((r >> 3) << 9) | (kc << 7) | ((r & 7) << 4);
    r = wc * 64 + f * 16 + fr;
    b_o[f] = ((r >> 3) << 9) | (kc << 7) | ((r & 7) << 4);
  }

  f32x4 acc[4][4];
  #pragma unroll
  for (int i = 0; i < 4; ++i)
    #pragma unroll
    for (int j = 0; j < 4; ++j) acc[i][j] = (f32x4){0.f, 0.f, 0.f, 0.f};

  char* const Lp = (char*)&sh.stage[0][0];
  #define PL(b, p) (Lp + ((b) * 49152 + (p)))

  #define STAGE(buf, ks) { const size_t kb = (size_t)(ks) * 64; \
    gl_lds16(gAh + aoff0 + kb, PL(buf,0)     + dstA0); \
    gl_lds16(gAh + aoff1 + kb, PL(buf,0)     + dstA1); \
    gl_lds16(gAl + aoff0 + kb, PL(buf,16384) + dstA0); \
    gl_lds16(gAl + aoff1 + kb, PL(buf,16384) + dstA1); \
    gl_lds16(gBh + boff  + kb, PL(buf,32768) + dstB); \
    gl_lds16(gBl + boff  + kb, PL(buf,40960) + dstB); }

  bf16x8 ah0[4], bh0[4], ah1[4], bh1[4];
  bf16x8 al[4], bl[4];

  #define RD_C1(AH, BH, buf) { \
    _Pragma("unroll") \
    for (int f = 0; f < 4; ++f) { \
      AH[f] = *(const bf16x8*)(PL(buf,0)     + a_o[f]); \
      BH[f] = *(const bf16x8*)(PL(buf,32768) + b_o[f]); \
    } }
  #define RD_C2(buf) { \
    _Pragma("unroll") \
    for (int f = 0; f < 4; ++f) { \
      al[f] = *(const bf16x8*)(PL(buf,16384) + a_o[f]); \
      bl[f] = *(const bf16x8*)(PL(buf,40960) + b_o[f]); \
    } }

  #define MM16(AA, BBV) { \
    _Pragma("unroll") \
    for (int i = 0; i < 4; ++i) \
      _Pragma("unroll") \
      for (int j = 0; j < 4; ++j) \
        acc[i][j] = __builtin_amdgcn_mfma_f32_16x16x32_bf16(AA[i], BBV[j], acc[i][j], 0,0,0); }

  #define ITER(KS, B, BN, AHc, BHc, AHn, BHn, VM, DOSTAGE, DONEXT) { \
    RD_C2(B); \
    __builtin_amdgcn_sched_barrier(0); \
    asm volatile("s_waitcnt lgkmcnt(8)" ::: "memory"); \
    __builtin_amdgcn_sched_barrier(0); \
    __builtin_amdgcn_s_setprio(1); \
    MM16(AHc, BHc); \
    __builtin_amdgcn_s_setprio(0); \
    __builtin_amdgcn_sched_barrier(0); \
    asm volatile("s_waitcnt lgkmcnt(0)" ::: "memory"); \
    __builtin_amdgcn_sched_barrier(0); \
    __builtin_amdgcn_s_barrier(); \
    if (DOSTAGE) STAGE(B, (KS)+3); \
    if (VM == 12)     { asm volatile("s_waitcnt vmcnt(12)" ::: "memory"); } \
    else if (VM == 6) { asm volatile("s_waitcnt vmcnt(6)"  ::: "memory"); } \
    else if (VM == 0) { asm volatile("s_waitcnt vmcnt(0)"  ::: "memory"); } \
    if (VM >= 0) { __builtin_amdgcn_sched_barrier(0); __builtin_amdgcn_s_barrier(); } \
    if (DONEXT) RD_C1(AHn, BHn, BN); \
    __builtin_amdgcn_s_setprio(1); \
    MM16(AHc, bl); \
    MM16(al, BHc); \
    __builtin_amdgcn_s_setprio(0); \
  }

  STAGE(0, 0);
  STAGE(1, 1);
  STAGE(2, 2);
  asm volatile("s_waitcnt vmcnt(12)" ::: "memory");
  __builtin_amdgcn_sched_barrier(0);
  __builtin_amdgcn_s_barrier();
  RD_C1(ah0, bh0, 0);

  for (int kk = 0; kk < 24; kk += 6) {
    ITER(kk+0, 0, 1, ah0, bh0, ah1, bh1, 12, 1, 1);
    ITER(kk+1, 1, 2, ah1, bh1, ah0, bh0, 12, 1, 1);
    ITER(kk+2, 2, 0, ah0, bh0, ah1, bh1, 12, 1, 1);
    ITER(kk+3, 0, 1, ah1, bh1, ah0, bh0, 12, 1, 1);
    ITER(kk+4, 1, 2, ah0, bh0, ah1, bh1, 12, 1, 1);
    ITER(kk+5, 2, 0, ah1, bh1, ah0, bh0, 12, 1, 1);
  }
  ITER(24, 0, 1, ah0, bh0, ah1, bh1, 12, 1, 1);
  ITER(25, 1, 2, ah1, bh1, ah0, bh0, 12, 1, 1);
  ITER(26, 2, 0, ah0, bh0, ah1, bh1, 12, 1, 1);
  ITER(27, 0, 1, ah1, bh1, ah0, bh0, 12, 1, 1);
  ITER(28, 1, 2, ah0, bh0, ah1, bh1, 12, 1, 1);
  ITER(29, 2, 0, ah1, bh1, ah0, bh0,  6, 0, 1);
  ITER(30, 0, 1, ah0, bh0, ah1, bh1,  0, 0, 1);
  ITER(31, 1, 2, ah1, bh1, ah0, bh0, -1, 0, 0);
  #undef PL
  #undef STAGE
  #undef RD_C1
  #undef RD_C2
  #undef MM16
  #undef ITER

  const int r4 = (lane >> 4) << 2;
  #pragma unroll
  for (int hh = 0; hh < 2; ++hh) {
    #pragma unroll
    for (int plane = 0; plane < 2; ++plane) {
      __syncthreads();
      if ((wr >> 1) == hh) {
        #pragma unroll
        for (int j = 0; j < 4; ++j) {
          const int col_l = wc*64 + j*16 + fr;
          const float bv = P.bias[n0 + col_l];
          #pragma unroll
          for (int i = 0; i < 4; ++i) {
            const int rl0 = (wr & 1)*64 + i*16 + r4;
            #pragma unroll
            for (int v = 0; v < 4; ++v) {
              const float val = (acc[i][j][v] + bv) * P.scale;
              const unsigned u = __float_as_uint(val);
              unsigned sv;
              if (plane == 0) { sv = u >> 16; }
              else {
                const float rres = val - __uint_as_float(u & 0xFFFF0000u);
                unsigned ur = __float_as_uint(rres);
                ur += ((ur >> 16) & 1u) + 0x7FFFu; sv = ur >> 16;
              }
              const int rl = rl0 + v;
              sh.ep[rl][(((col_l >> 3) ^ (rl & 7)) << 3) + (col_l & 7)] =
                  (unsigned short)sv;
            }
          }
        }
      }
      __syncthreads();
      unsigned short* const OUT = plane ? P.outLo : P.outHi;
      #pragma unroll
      for (int u2 = 0; u2 < 4; ++u2) {
        const int chunk = u2 * 512 + tid;
        const int rr = chunk >> 4, c16 = chunk & 15;
        const bf16x8 vv = *(const bf16x8*)&sh.ep[rr][(c16 ^ (rr & 7)) << 3];
        *(bf16x8*)&OUT[(size_t)(m0 + hh*128 + rr) * EE + n0 + c16*8] = vv;
      }
    }
  }
}

// ---------------------------------------------------------------------------
// MFMA fused no-overlap sliding-chunk attention (R11 base: plain 3D grid,
// no setprio/swizzle -- R13's A/B showed those were net-negative here).
// R14 change: V staging re-mapped 1k x 8d -> 2k x 4d per thread, so each
// k-pair lands in adjacent shorts of the V^T layout -> ds_write_b32 pairs:
// 16 b16 scatter ops -> 8 b32 ops per thread per tile (the largest LDS-pipe
// term in this LDS-bound kernel). Same final layout -> bit-identical.
// ---------------------------------------------------------------------------
__global__ __launch_bounds__(256) void attn_mfma(
    const unsigned short* __restrict__ Qh_g, const unsigned short* __restrict__ Ql_g,
    const unsigned short* __restrict__ Kh_g, const unsigned short* __restrict__ Kl_g,
    const unsigned short* __restrict__ Vh_g, const unsigned short* __restrict__ Vl_g,
    float* __restrict__ Og)
{
  __shared__ __align__(16) unsigned short Kf[2][2048];   // [plane][frag-linear]
  __shared__ __align__(16) unsigned short Vt[2][2048];   // [plane][V^T frag-linear, swz]
  __shared__ unsigned long long Pscr[4][256];            // per wave: hi[0:128) lo[128:256)

  const int c = blockIdx.x, h = blockIdx.y, bz = blockIdx.z;
  const int b = bz >> 1, qh = bz & 1;          // batch, q-half of the chunk
  const int tid = threadIdx.x;
  const int lane = tid & 63, wid = tid >> 6;
  const int g = lane >> 4, lq = lane & 15;

  const size_t chunk0 = (size_t)(b * NCC + c) * WW;   // chunk row start
  const size_t qrow0  = chunk0 + (size_t)qh * 128;    // this block's q rows
  const int colh = h * DD;

  // ---- Q B-frags (col q = lane&15, k-elems d = g*8..), 2 subtiles/wave ----
  bf16x8 qfh[2][2], qfl[2][2];
  #pragma unroll
  for (int s = 0; s < 2; ++s)
    #pragma unroll
    for (int ch = 0; ch < 2; ++ch) {
      const size_t off = (qrow0 + wid*32 + s*16 + lq) * EE + colh + ch*32 + g*8;
      qfh[s][ch] = *(const bf16x8*)(Qh_g + off);
      qfl[s][ch] = *(const bf16x8*)(Ql_g + off);
    }

  f32x4 Oa[4][2];   // [d-subtile][q-subtile]
  #pragma unroll
  for (int i = 0; i < 4; ++i)
    #pragma unroll
    for (int j = 0; j < 2; ++j) Oa[i][j] = (f32x4){0.f, 0.f, 0.f, 0.f};
  float m[2], lsum[2];
  #pragma unroll
  for (int s = 0; s < 2; ++s) { m[s] = -1e30f; lsum[s] = 0.f; }

  // K staging: wave wid stages A-frag f=wid (kh=wid&1, ch=wid>>1), frag-linear.
  const int kK = 16*(wid & 1) + lq;
  const int dK = 32*(wid >> 1) + g*8;
  // V staging (2k x 4d per thread): kV = 2*(tid>>4), dV = 4*(tid&15).
  // k-pair -> adjacent shorts in V^T layout -> one b32 write per d.
  const int kV = (tid >> 4) << 1;          // 0,2,..,30
  const int dV = (tid & 15) << 2;          // 0,4,..,60
  // chunk c(k,d) = (d>>4)*64 + (k>>3)*16 + (d&15); swizzle bits {6,4,3}
  // constant across the 4-aligned d-quad (no carries).
  const int C0v = ((dV >> 4) << 6) | ((kV >> 3) << 4) | (dV & 15);
  const int swV = (((dV >> 4) & 1) << 2) | (((kV >> 3) & 1) << 1) | ((dV >> 3) & 1);
  const int kvl = kV & 7;                  // even

  const long krow0_base = (long)chunk0 - WW;   // key window is per CHUNK
  const int t0 = (c == 0) ? 8 : 0;
  const int tN = (c == NCC-1) ? 16 : 24;

  uint4 rkh, rkl;
  uint2 rvh0, rvh1, rvl0, rvl1;   // V rows kV, kV+1 (4 d each), hi/lo planes
  {
    const long kr = krow0_base + (long)t0*32;
    const size_t offK = (size_t)(kr + kK) * EE + colh + dK;
    const size_t offV = (size_t)(kr + kV) * EE + colh + dV;
    rkh = *(const uint4*)(Kh_g + offK); rkl = *(const uint4*)(Kl_g + offK);
    rvh0 = *(const uint2*)(Vh_g + offV); rvh1 = *(const uint2*)(Vh_g + offV + EE);
    rvl0 = *(const uint2*)(Vl_g + offV); rvl1 = *(const uint2*)(Vl_g + offV + EE);
  }

  for (int tt = t0; tt < tN; ++tt) {
    __syncthreads();   // all waves done reading previous tile's Kf/Vt
    *(uint4*)&Kf[0][wid*512 + lane*8] = rkh;
    *(uint4*)&Kf[1][wid*512 + lane*8] = rkl;
    {
      // b32 V scatter: value j packs (k=kV, d=dV+j) | (k=kV+1, d=dV+j)<<16
      const unsigned h0[2] = {rvh0.x, rvh0.y};
      const unsigned h1[2] = {rvh1.x, rvh1.y};
      const unsigned l0[2] = {rvl0.x, rvl0.y};
      const unsigned l1[2] = {rvl1.x, rvl1.y};
      #pragma unroll
      for (int j = 0; j < 4; ++j) {
        const int sft = (j & 1) * 16, wsel = j >> 1;
        const unsigned sH0 = (h0[wsel] >> sft) & 0xFFFFu;
        const unsigned sH1 = (h1[wsel] >> sft) & 0xFFFFu;
        const unsigned sL0 = (l0[wsel] >> sft) & 0xFFFFu;
        const unsigned sL1 = (l1[wsel] >> sft) & 0xFFFFu;
        const int csw = (C0v + j) ^ swV;
        const int u32i = csw * 4 + (kvl >> 1);   // u32 index within plane
        ((unsigned*)&Vt[0][0])[u32i] = sH0 | (sH1 << 16);
        ((unsigned*)&Vt[1][0])[u32i] = sL0 | (sL1 << 16);
      }
    }
    __syncthreads();   // tile ready

    if (tt + 1 < tN) {   // issue next tile's loads early (hide HBM latency)
      const long kr = krow0_base + (long)(tt+1)*32;
      const size_t offK = (size_t)(kr + kK) * EE + colh + dK;
      const size_t offV = (size_t)(kr + kV) * EE + colh + dV;
      rkh = *(const uint4*)(Kh_g + offK); rkl = *(const uint4*)(Kl_g + offK);
      rvh0 = *(const uint2*)(Vh_g + offV); rvh1 = *(const uint2*)(Vh_g + offV + EE);
      rvl0 = *(const uint2*)(Vl_g + offV); rvl1 = *(const uint2*)(Vl_g + offV + EE);
    }

    // K A-frags: contiguous wave-wide ds_read_b128
    bf16x8 kfh[2][2], kfl[2][2];
    #pragma unroll
    for (int f = 0; f < 4; ++f) {
      const int o = f*512 + lane*8;
      kfh[f & 1][f >> 1] = *(const bf16x8*)&Kf[0][o];
      kfl[f & 1][f >> 1] = *(const bf16x8*)&Kf[1][o];
    }

    // V^T A-frags: contiguous b128 with matching XOR chunk swizzle.
    bf16x8 vfh[4], vfl[4];
    #pragma unroll
    for (int ds = 0; ds < 4; ++ds) {
      const int rch = ds*64 + g*16 + lq;
      const int rsw = (((rch >> 6) & 1) << 2) | (((rch >> 4) & 1) << 1) | ((rch >> 3) & 1);
      vfh[ds] = *(const bf16x8*)&Vt[0][(rch ^ rsw) * 8];
      vfl[ds] = *(const bf16x8*)&Vt[1][(rch ^ rsw) * 8];
    }

    #pragma unroll
    for (int s = 0; s < 2; ++s) {
      // ---- QK^T (3-pass split), D: col q = lane&15, key = g*4 + reg ----
      f32x4 ac0 = (f32x4){0.f,0.f,0.f,0.f}, ac1 = (f32x4){0.f,0.f,0.f,0.f};
      #pragma unroll
      for (int ch = 0; ch < 2; ++ch) {
        ac0 = __builtin_amdgcn_mfma_f32_16x16x32_bf16(kfh[0][ch], qfh[s][ch], ac0, 0,0,0);
        ac0 = __builtin_amdgcn_mfma_f32_16x16x32_bf16(kfh[0][ch], qfl[s][ch], ac0, 0,0,0);
        ac0 = __builtin_amdgcn_mfma_f32_16x16x32_bf16(kfl[0][ch], qfh[s][ch], ac0, 0,0,0);
        ac1 = __builtin_amdgcn_mfma_f32_16x16x32_bf16(kfh[1][ch], qfh[s][ch], ac1, 0,0,0);
        ac1 = __builtin_amdgcn_mfma_f32_16x16x32_bf16(kfh[1][ch], qfl[s][ch], ac1, 0,0,0);
        ac1 = __builtin_amdgcn_mfma_f32_16x16x32_bf16(kfl[1][ch], qfh[s][ch], ac1, 0,0,0);
      }

      // ---- online softmax (per q-column, reduce over the 4 g-lanes) ----
      float tmax = fmaxf(fmaxf(fmaxf(ac0[0],ac0[1]), fmaxf(ac0[2],ac0[3])),
                         fmaxf(fmaxf(ac1[0],ac1[1]), fmaxf(ac1[2],ac1[3])));
      tmax = fmaxf(tmax, __shfl_xor(tmax, 16));
      tmax = fmaxf(tmax, __shfl_xor(tmax, 32));
      const float mo = m[s];
      const float mn = fmaxf(mo, tmax);
      m[s] = mn;
      const float sc = __expf(mo - mn);   // exp(-1e30 - x) == 0
      float pv[8];
      #pragma unroll
      for (int r = 0; r < 4; ++r) { pv[r] = __expf(ac0[r] - mn); pv[4+r] = __expf(ac1[r] - mn); }
      float ps = 0.f;
      #pragma unroll
      for (int r = 0; r < 8; ++r) ps += pv[r];
      lsum[s] = lsum[s] * sc + ps;
      #pragma unroll
      for (int ds = 0; ds < 4; ++ds) Oa[ds][s] *= sc;

      // ---- pack P hi/lo, route via native-u64 LDS scratch ----
      unsigned hb[8], lb[8];
      #pragma unroll
      for (int r = 0; r < 8; ++r) {
        hb[r] = bf16rne(pv[r]);
        const float rr = pv[r] - __uint_as_float(hb[r] << 16);
        lb[r] = bf16rne(rr);
      }
      const int pq = (g >> 1)*32 + lq*2 + (g & 1);   // u64 index; *4 = short idx
      Pscr[wid][pq]            = pack64(hb[0],hb[1],hb[2],hb[3]);
      Pscr[wid][pq + 64]       = pack64(hb[4],hb[5],hb[6],hb[7]);
      Pscr[wid][128 + pq]      = pack64(lb[0],lb[1],lb[2],lb[3]);
      Pscr[wid][128 + pq + 64] = pack64(lb[4],lb[5],lb[6],lb[7]);
      asm volatile("" ::: "memory");   // compiler fence: writes before reads
      union U8 { unsigned long long q[2]; bf16x8 v; };
      U8 uh, ul;
      uh.q[0] = Pscr[wid][lane*2];       uh.q[1] = Pscr[wid][lane*2 + 1];
      ul.q[0] = Pscr[wid][128 + lane*2]; ul.q[1] = Pscr[wid][128 + lane*2 + 1];
      const bf16x8 pbh = uh.v;
      const bf16x8 pbl = ul.v;

      // ---- PV (3-pass split): O^T[d][q] += V^T · P^T ----
      #pragma unroll
      for (int ds = 0; ds < 4; ++ds) {
        Oa[ds][s] = __builtin_amdgcn_mfma_f32_16x16x32_bf16(vfh[ds], pbh, Oa[ds][s], 0,0,0);
        Oa[ds][s] = __builtin_amdgcn_mfma_f32_16x16x32_bf16(vfl[ds], pbh, Oa[ds][s], 0,0,0);
        Oa[ds][s] = __builtin_amdgcn_mfma_f32_16x16x32_bf16(vfh[ds], pbl, Oa[ds][s], 0,0,0);
      }
    }
  }

  // ---- epilogue: fold zero-pad keys, normalize, store ----
  #pragma unroll
  for (int s = 0; s < 2; ++s) {
    float ls = lsum[s];
    ls += __shfl_xor(ls, 16);
    ls += __shfl_xor(ls, 32);
    const int x = qh*128 + wid*32 + s*16 + lq;   // row within the chunk
    const float nz = (c == 0) ? (float)x
                   : ((c == NCC-1) ? (float)(WW - 1 - x) : 0.f);
    ls += nz * __expf(0.f - m[s]);
    const float inv = 1.f / ls;
    float* op = Og + (chunk0 + x) * EE + colh;
    #pragma unroll
    for (int ds = 0; ds < 4; ++ds) {
      float4 r;
      r.x = Oa[ds][s][0]*inv; r.y = Oa[ds][s][1]*inv;
      r.z = Oa[ds][s][2]*inv; r.w = Oa[ds][s][3]*inv;
      *(float4*)(op + ds*16 + g*4) = r;
    }
  }
}

extern "C" void kernel_launch(void* const* d_in, const int* in_sizes, int n_in,
                              void* d_out, int out_size, void* d_ws, size_t ws_size,
                              hipStream_t stream) {
    const float* hs = (const float*)d_in[0];
    const float* Wq = (const float*)d_in[1];
    const float* bq = (const float*)d_in[2];
    const float* Wk = (const float*)d_in[3];
    const float* bk = (const float*)d_in[4];
    const float* Wv = (const float*)d_in[5];
    const float* bv = (const float*)d_in[6];
    float* out = (float*)d_out;

    const size_t mat  = (size_t)MTOT * EE;   // 8388608
    const size_t wmat = (size_t)EE * EE;     // 1048576

    unsigned short* w = (unsigned short*)d_ws;
    unsigned short* Ahi = w;            unsigned short* Alo = Ahi + mat;
    unsigned short* Wqh = Alo + mat;    unsigned short* Wql = Wqh + wmat;
    unsigned short* Wkh = Wql + wmat;   unsigned short* Wkl = Wkh + wmat;
    unsigned short* Wvh = Wkl + wmat;   unsigned short* Wvl = Wvh + wmat;
    unsigned short* Qhb = Wvl + wmat;   unsigned short* Qlb = Qhb + mat;
    unsigned short* Khb = Qlb + mat;    unsigned short* Klb = Khb + mat;
    unsigned short* Vhb = Klb + mat;    unsigned short* Vlb = Vhb + mat;
    // total ws: (8*mat + 6*wmat)*2B = 140 MB

    // one dispatch for all four splits: 8192 (hs) + 3*1024 (weights) blocks
    split_all<<<8192 + 3*1024, 256, 0, stream>>>(
        hs, Wq, Wk, Wv, Ahi, Alo, Wqh, Wql, Wkh, Wkl, Wvh, Wvl);

    ProjArgs pq{Wqh, Wql, bq, Qhb, Qlb, 0.125f};   // 1/sqrt(64)
    ProjArgs pk{Wkh, Wkl, bk, Khb, Klb, 1.0f};
    ProjArgs pv{Wvh, Wvl, bv, Vhb, Vlb, 1.0f};
    dim3 g(MTOT/256, EE/128, 3);
    mfma_proj<<<g, 512, 0, stream>>>(Ahi, Alo, pq, pk, pv);

    dim3 ga(NCC, HH, BB*2);
    attn_mfma<<<ga, 256, 0, stream>>>(Qhb, Qlb, Khb, Klb, Vhb, Vlb, out);
}